// Round 3
// baseline (702.799 us; speedup 1.0000x reference)
//
#include <hip/hip_runtime.h>
#include <math.h>

#define N_NODES 50000
#define N_EDGES 800000
#define D_IN    128
#define ED_IN   64
#define HU      128   // H*U
#define NH      4
#define UD      32

#define NPB 8    // nodes per block in qkvg kernel
#define EPB 16   // edges per block in score kernel

static __device__ __forceinline__ unsigned short f2bf(float f) {
  unsigned u = __float_as_uint(f);
  unsigned r = (u + 0x7FFFu + ((u >> 16) & 1u)) >> 16;
  return (unsigned short)r;
}
static __device__ __forceinline__ float bf2f(unsigned s) {
  return __uint_as_float(s << 16);
}

// K0: segment offsets from sorted src. off[n] = lower_bound(src, n); off[N] = E.
__global__ __launch_bounds__(256) void offsets_kernel(
    const int* __restrict__ src, int* __restrict__ off) {
  const int e = blockIdx.x * 256 + threadIdx.x;
  if (e >= N_EDGES) return;
  const int s = src[e];
  const int prev = (e == 0) ? -1 : src[e - 1];
  for (int n = prev + 1; n <= s; ++n) off[n] = e;
  if (e == N_EDGES - 1)
    for (int n = s + 1; n <= N_NODES; ++n) off[n] = N_EDGES;
}

// K1: fused q/k/v projections + g matrix.
//   q  (fp32, + bq + be folded in so the be.k score term is free)
//   k,v stored bf16; g[n,h,i] = sum_u We[i,h*32+u]*k[n,h*32+u] stored bf16 [N,4,64]
__global__ __launch_bounds__(128) void qkvg_kernel(
    const float* __restrict__ x,
    const float* __restrict__ Wq, const float* __restrict__ bq,
    const float* __restrict__ Wk, const float* __restrict__ bk,
    const float* __restrict__ Wv, const float* __restrict__ bv,
    const float* __restrict__ be, const float* __restrict__ We,
    float* __restrict__ q, unsigned short* __restrict__ kbf,
    unsigned short* __restrict__ vbf, unsigned short* __restrict__ gbf) {
  const int base = blockIdx.x * NPB;
  const int t = threadIdx.x;
  __shared__ float xs[NPB][D_IN];
  for (int j = 0; j < NPB; ++j)
    xs[j][t] = x[(long)(base + j) * D_IN + t];
  __syncthreads();
  float aq[NPB], ak[NPB], av[NPB];
  const float bqt = bq[t] + be[t], bkt = bk[t], bvt = bv[t];
  for (int j = 0; j < NPB; ++j) { aq[j] = bqt; ak[j] = bkt; av[j] = bvt; }
  for (int i = 0; i < D_IN; ++i) {
    const float wq = Wq[i * HU + t];
    const float wk = Wk[i * HU + t];
    const float wv = Wv[i * HU + t];
    for (int j = 0; j < NPB; ++j) {
      const float xi = xs[j][i];
      aq[j] += xi * wq; ak[j] += xi * wk; av[j] += xi * wv;
    }
  }
  for (int j = 0; j < NPB; ++j) {
    const long o = (long)(base + j) * HU + t;
    q[o] = aq[j]; kbf[o] = f2bf(ak[j]); vbf[o] = f2bf(av[j]);
  }
  __syncthreads();
  for (int j = 0; j < NPB; ++j) xs[j][t] = ak[j];  // reuse xs as k staging
  __syncthreads();
  for (int r = 0; r < 2; ++r) {
    const int o = t + 128 * r;      // output index in [0,256)
    const int h = o >> 6, i = o & 63;
    float acc[NPB];
    for (int j = 0; j < NPB; ++j) acc[j] = 0.f;
    for (int u = 0; u < 32; ++u) {
      const float w = We[i * HU + h * 32 + u];
      for (int j = 0; j < NPB; ++j) acc[j] += w * xs[j][h * 32 + u];
    }
    for (int j = 0; j < NPB; ++j)
      gbf[(long)(base + j) * 256 + o] = f2bf(acc[j]);
  }
}

// K2: scores[e,h] = sum_u q'[s,h,u]*k[d,h,u] + sum_i ef[e,i]*g[d,h,i]
// k,g read as packed bf16x2. Thread t -> (h = t>>5, l = t&31).
__global__ __launch_bounds__(128) void score_kernel(
    const float* __restrict__ ef,
    const int* __restrict__ src, const int* __restrict__ dst,
    const float* __restrict__ q, const unsigned* __restrict__ k2,
    const unsigned* __restrict__ g2,
    float* __restrict__ scores) {
  const long base = (long)blockIdx.x * EPB;
  const int t = threadIdx.x;
  const int h = t >> 5, l = t & 31;
  __shared__ float efs[EPB][ED_IN];
  for (int r = 0; r < EPB; r += 2) {
    const int row = r + (t >> 6);
    const int col = t & 63;
    efs[row][col] = ef[(base + row) * ED_IN + col];
  }
  __syncthreads();
  const int ss = src[base + (t & 15)];
  const int dd = dst[base + (t & 15)];
  for (int j = 0; j < EPB; ++j) {
    const int s = __shfl(ss, j, 16);
    const int d = __shfl(dd, j, 16);
    float p = 0.f;
    if (l < 16) {
      const float2 qf = *(const float2*)(q + (long)s * HU + h * 32 + 2 * l);
      const unsigned kp = k2[(long)d * 64 + h * 16 + l];
      p = qf.x * bf2f(kp & 0xFFFFu) + qf.y * bf2f(kp >> 16);
    }
    const unsigned gp = g2[(long)d * 128 + h * 32 + l];
    const float2 ep = *(const float2*)&efs[j][2 * l];
    p += ep.x * bf2f(gp & 0xFFFFu) + ep.y * bf2f(gp >> 16);
    for (int off = 16; off > 0; off >>= 1) p += __shfl_down(p, off, 32);
    if (l == 0) scores[(base + j) * NH + h] = p;
  }
}

// K3: segmented softmax + attn*v aggregation + output GEMM + relu.
// One block (128 thr) per node; thread t -> (h = t>>5, l = t&31).
__global__ __launch_bounds__(128) void aggregate_kernel(
    const int* __restrict__ off, const int* __restrict__ dst,
    const float* __restrict__ scores, const unsigned short* __restrict__ vbf,
    const float* __restrict__ Wo, const float* __restrict__ bo,
    float* __restrict__ out) {
  const int n = blockIdx.x;
  const int t = threadIdx.x;
  const int h = t >> 5, l = t & 31;
  const int start = off[n], end = off[n + 1];

  float m = -INFINITY, ld = 0.f, acc = 0.f;
  for (int cs = start; cs < end; cs += 32) {
    const int ce = min(cs + 32, end);
    const int e = cs + l;
    const bool live = (e < ce);
    float sc = live ? scores[(long)e * NH + h] : -INFINITY;
    int dl = live ? dst[e] : 0;
    float mc = sc;
    for (int o = 16; o > 0; o >>= 1) mc = fmaxf(mc, __shfl_xor(mc, o, 32));
    const float nm = fmaxf(m, mc);
    const float w = __expf(sc - nm);       // 0 for dead/padded lanes
    const float corr = __expf(m - nm);     // 0 on first chunk
    float ws = w;
    for (int o = 16; o > 0; o >>= 1) ws += __shfl_xor(ws, o, 32);
    ld = ld * corr + ws;
    acc *= corr;
    m = nm;
    const int cnt = ce - cs;
    // padded to unroll-8: lanes >= cnt have w=0, dl=0 -> harmless cached loads
    for (int j = 0; j < cnt; j += 8) {
#pragma unroll
      for (int jj = 0; jj < 8; ++jj) {
        const float wj = __shfl(w, j + jj, 32);
        const int dj = __shfl(dl, j + jj, 32);
        acc += wj * bf2f((unsigned)vbf[(long)dj * HU + t]);
      }
    }
  }
  const float inv = (ld > 0.f) ? 1.f / ld : 0.f;
  acc *= inv;

  __shared__ float att[HU];
  __shared__ float part[HU];
  att[t] = acc;
  __syncthreads();
  const int o = t & 31, fs = t >> 5;
  float po = 0.f;
  for (int j = 0; j < 32; ++j)
    po += att[fs * 32 + j] * Wo[(fs * 32 + j) * UD + o];
  part[t] = po;
  __syncthreads();
  if (t < UD) {
    const float oo = part[t] + part[t + 32] + part[t + 64] + part[t + 96] + bo[t];
    out[(long)n * UD + t] = fmaxf(oo, 0.f);
  }
}

extern "C" void kernel_launch(void* const* d_in, const int* in_sizes, int n_in,
                              void* d_out, int out_size, void* d_ws, size_t ws_size,
                              hipStream_t stream) {
  const float* x  = (const float*)d_in[0];
  const int*   ei = (const int*)d_in[1];
  const float* ef = (const float*)d_in[2];
  const float* Wq = (const float*)d_in[3];
  const float* bq = (const float*)d_in[4];
  const float* Wk = (const float*)d_in[5];
  const float* bk = (const float*)d_in[6];
  const float* Wv = (const float*)d_in[7];
  const float* bv = (const float*)d_in[8];
  const float* We = (const float*)d_in[9];
  const float* be = (const float*)d_in[10];
  const float* Wo = (const float*)d_in[11];
  const float* bo = (const float*)d_in[12];
  float* out = (float*)d_out;

  const int* src = ei;             // edge_index[0]
  const int* dst = ei + N_EDGES;   // edge_index[1]

  // ws layout: q fp32 [N*128] | kbf [N*128] | vbf [N*128] | gbf [N*256] | scores [E*4] | off
  float* q = (float*)d_ws;
  unsigned short* kbf = (unsigned short*)(q + (long)N_NODES * HU);
  unsigned short* vbf = kbf + (long)N_NODES * HU;
  unsigned short* gbf = vbf + (long)N_NODES * HU;
  float* scores = (float*)(gbf + (long)N_NODES * 256);
  int* off = (int*)(scores + (long)N_EDGES * NH);

  offsets_kernel<<<(N_EDGES + 255) / 256, 256, 0, stream>>>(src, off);
  qkvg_kernel<<<N_NODES / NPB, 128, 0, stream>>>(x, Wq, bq, Wk, bk, Wv, bv, be, We,
                                                 q, kbf, vbf, gbf);
  score_kernel<<<N_EDGES / EPB, 128, 0, stream>>>(ef, src, dst, q,
                                                  (const unsigned*)kbf,
                                                  (const unsigned*)gbf, scores);
  aggregate_kernel<<<N_NODES, 128, 0, stream>>>(off, dst, scores, vbf, Wo, bo, out);
}

// Round 4
// 688.321 us; speedup vs baseline: 1.0210x; 1.0210x over previous
//
#include <hip/hip_runtime.h>
#include <math.h>

#define N_NODES 50000
#define N_EDGES 800000
#define D_IN    128
#define ED_IN   64
#define HU      128   // H*U
#define NH      4
#define UD      32

#define NPB 8    // nodes per block in qkvg kernel

static __device__ __forceinline__ unsigned short f2bf(float f) {
  unsigned u = __float_as_uint(f);
  unsigned r = (u + 0x7FFFu + ((u >> 16) & 1u)) >> 16;
  return (unsigned short)r;
}
static __device__ __forceinline__ float bf_lo(unsigned u) {
  return __uint_as_float(u << 16);
}
static __device__ __forceinline__ float bf_hi(unsigned u) {
  return __uint_as_float(u & 0xFFFF0000u);
}
// 8-element dot: fp32 a0|a1 against 8 bf16 packed in uint4
static __device__ __forceinline__ float dot8(float4 a0, float4 a1, uint4 kk) {
  return a0.x * bf_lo(kk.x) + a0.y * bf_hi(kk.x)
       + a0.z * bf_lo(kk.y) + a0.w * bf_hi(kk.y)
       + a1.x * bf_lo(kk.z) + a1.y * bf_hi(kk.z)
       + a1.z * bf_lo(kk.w) + a1.w * bf_hi(kk.w);
}

// K0: segment offsets from sorted src. off[n] = lower_bound(src, n); off[N] = E.
__global__ __launch_bounds__(256) void offsets_kernel(
    const int* __restrict__ src, int* __restrict__ off) {
  const int e = blockIdx.x * 256 + threadIdx.x;
  if (e >= N_EDGES) return;
  const int s = src[e];
  const int prev = (e == 0) ? -1 : src[e - 1];
  for (int n = prev + 1; n <= s; ++n) off[n] = e;
  if (e == N_EDGES - 1)
    for (int n = s + 1; n <= N_NODES; ++n) off[n] = N_EDGES;
}

// K1: fused q/k/v projections + g matrix.
//   q fp32 (bq+be folded in); k,v bf16; g[n,h,i] = sum_u We[i,h*32+u]*k[n,h*32+u], bf16 [N,4,64]
__global__ __launch_bounds__(128) void qkvg_kernel(
    const float* __restrict__ x,
    const float* __restrict__ Wq, const float* __restrict__ bq,
    const float* __restrict__ Wk, const float* __restrict__ bk,
    const float* __restrict__ Wv, const float* __restrict__ bv,
    const float* __restrict__ be, const float* __restrict__ We,
    float* __restrict__ q, unsigned short* __restrict__ kbf,
    unsigned short* __restrict__ vbf, unsigned short* __restrict__ gbf) {
  const int base = blockIdx.x * NPB;
  const int t = threadIdx.x;
  __shared__ float xs[NPB][D_IN];
  for (int j = 0; j < NPB; ++j)
    xs[j][t] = x[(long)(base + j) * D_IN + t];
  __syncthreads();
  float aq[NPB], ak[NPB], av[NPB];
  const float bqt = bq[t] + be[t], bkt = bk[t], bvt = bv[t];
  for (int j = 0; j < NPB; ++j) { aq[j] = bqt; ak[j] = bkt; av[j] = bvt; }
  for (int i = 0; i < D_IN; ++i) {
    const float wq = Wq[i * HU + t];
    const float wk = Wk[i * HU + t];
    const float wv = Wv[i * HU + t];
    for (int j = 0; j < NPB; ++j) {
      const float xi = xs[j][i];
      aq[j] += xi * wq; ak[j] += xi * wk; av[j] += xi * wv;
    }
  }
  for (int j = 0; j < NPB; ++j) {
    const long o = (long)(base + j) * HU + t;
    q[o] = aq[j]; kbf[o] = f2bf(ak[j]); vbf[o] = f2bf(av[j]);
  }
  __syncthreads();
  for (int j = 0; j < NPB; ++j) xs[j][t] = ak[j];  // reuse xs as k staging
  __syncthreads();
  for (int r = 0; r < 2; ++r) {
    const int o = t + 128 * r;      // output index in [0,256)
    const int h = o >> 6, i = o & 63;
    float acc[NPB];
    for (int j = 0; j < NPB; ++j) acc[j] = 0.f;
    for (int u = 0; u < 32; ++u) {
      const float w = We[i * HU + h * 32 + u];
      for (int j = 0; j < NPB; ++j) acc[j] += w * xs[j][h * 32 + u];
    }
    for (int j = 0; j < NPB; ++j)
      gbf[(long)(base + j) * 256 + o] = f2bf(acc[j]);
  }
}

// K2: one thread per (edge, head). scores[e,h] = q'[s,h,:]·k[d,h,:] + ef[e,:]·g[d,h,:]
// k,g bf16-packed; all loads wide & independent, no cross-lane ops.
__global__ __launch_bounds__(256) void score_kernel(
    const float* __restrict__ ef,
    const int* __restrict__ src, const int* __restrict__ dst,
    const float* __restrict__ q, const unsigned* __restrict__ k2,
    const unsigned* __restrict__ g2,
    float* __restrict__ scores) {
  const int tid = blockIdx.x * 256 + threadIdx.x;
  const int e = tid >> 2;
  const int h = tid & 3;
  const int s = src[e];
  const int d = dst[e];

  // scattered contiguous loads first: 4+8 independent uint4s in flight
  const uint4* kp = (const uint4*)(k2 + (long)d * 64 + h * 16);
  const uint4* gp = (const uint4*)(g2 + (long)d * 128 + h * 32);
  uint4 kk0 = kp[0], kk1 = kp[1], kk2 = kp[2], kk3 = kp[3];
  uint4 gg0 = gp[0], gg1 = gp[1], gg2 = gp[2], gg3 = gp[3];
  uint4 gg4 = gp[4], gg5 = gp[5], gg6 = gp[6], gg7 = gp[7];

  const float4* qp = (const float4*)(q + (long)s * HU + h * 32);
  const float4* ep = (const float4*)(ef + (long)e * ED_IN);

  float p = 0.f;
  p += dot8(qp[0], qp[1], kk0);
  p += dot8(qp[2], qp[3], kk1);
  p += dot8(qp[4], qp[5], kk2);
  p += dot8(qp[6], qp[7], kk3);
  p += dot8(ep[0],  ep[1],  gg0);
  p += dot8(ep[2],  ep[3],  gg1);
  p += dot8(ep[4],  ep[5],  gg2);
  p += dot8(ep[6],  ep[7],  gg3);
  p += dot8(ep[8],  ep[9],  gg4);
  p += dot8(ep[10], ep[11], gg5);
  p += dot8(ep[12], ep[13], gg6);
  p += dot8(ep[14], ep[15], gg7);
  scores[tid] = p;   // coalesced: [e][h]
}

// K3: segmented softmax + attn*v aggregation + output GEMM + relu.
// One block (128 thr) per node; t -> (h = t>>5, l = t&31). Chunk=64 edges via LDS.
__global__ __launch_bounds__(128) void aggregate_kernel(
    const int* __restrict__ off, const int* __restrict__ dst,
    const float* __restrict__ scores, const unsigned short* __restrict__ vbf,
    const float* __restrict__ Wo, const float* __restrict__ bo,
    float* __restrict__ out) {
  const int n = blockIdx.x;
  const int t = threadIdx.x;
  const int h = t >> 5, l = t & 31;
  const int start = off[n], end = off[n + 1];

  __shared__ float wl[64][NH];
  __shared__ int   dl[64];

  float m = -INFINITY, ld = 0.f, acc = 0.f;
  for (int cs = start; cs < end; cs += 64) {
    const int cnt = min(64, end - cs);
    // two edges per thread within the chunk
    const int e0 = cs + l, e1 = cs + 32 + l;
    const float sc0 = (l      < cnt) ? scores[(long)e0 * NH + h] : -INFINITY;
    const float sc1 = (32 + l < cnt) ? scores[(long)e1 * NH + h] : -INFINITY;
    float mc = fmaxf(sc0, sc1);
    for (int o = 16; o > 0; o >>= 1) mc = fmaxf(mc, __shfl_xor(mc, o, 32));
    const float nm = fmaxf(m, mc);          // finite: cnt >= 1
    const float corr = __expf(m - nm);      // 0 on first chunk
    const float w0 = __expf(sc0 - nm);      // 0 for padded lanes
    const float w1 = __expf(sc1 - nm);
    float ws = w0 + w1;
    for (int o = 16; o > 0; o >>= 1) ws += __shfl_xor(ws, o, 32);
    ld = ld * corr + ws;
    acc *= corr;
    m = nm;
    wl[l][h] = w0;
    wl[32 + l][h] = w1;
    if (t < 64) dl[t] = (t < cnt) ? dst[cs + t] : 0;
    __syncthreads();
    // 16 independent gathers in flight; padded entries have w=0, dj=0 (harmless)
    for (int j = 0; j < cnt; j += 16) {
#pragma unroll
      for (int jj = 0; jj < 16; ++jj) {
        const float wj = wl[j + jj][h];
        const int dj = dl[j + jj];
        acc += wj * bf_lo((unsigned)vbf[(long)dj * HU + t]);
      }
    }
    __syncthreads();
  }
  const float inv = (ld > 0.f) ? 1.f / ld : 0.f;
  acc *= inv;

  __shared__ float att[HU];
  __shared__ float part[HU];
  att[t] = acc;
  __syncthreads();
  const int o = t & 31, fs = t >> 5;
  float po = 0.f;
  for (int j = 0; j < 32; ++j)
    po += att[fs * 32 + j] * Wo[(fs * 32 + j) * UD + o];
  part[t] = po;
  __syncthreads();
  if (t < UD) {
    const float oo = part[t] + part[t + 32] + part[t + 64] + part[t + 96] + bo[t];
    out[(long)n * UD + t] = fmaxf(oo, 0.f);
  }
}

extern "C" void kernel_launch(void* const* d_in, const int* in_sizes, int n_in,
                              void* d_out, int out_size, void* d_ws, size_t ws_size,
                              hipStream_t stream) {
  const float* x  = (const float*)d_in[0];
  const int*   ei = (const int*)d_in[1];
  const float* ef = (const float*)d_in[2];
  const float* Wq = (const float*)d_in[3];
  const float* bq = (const float*)d_in[4];
  const float* Wk = (const float*)d_in[5];
  const float* bk = (const float*)d_in[6];
  const float* Wv = (const float*)d_in[7];
  const float* bv = (const float*)d_in[8];
  const float* We = (const float*)d_in[9];
  const float* be = (const float*)d_in[10];
  const float* Wo = (const float*)d_in[11];
  const float* bo = (const float*)d_in[12];
  float* out = (float*)d_out;

  const int* src = ei;             // edge_index[0]
  const int* dst = ei + N_EDGES;   // edge_index[1]

  // ws layout: q fp32 [N*128] | kbf [N*128] | vbf [N*128] | gbf [N*256] | scores [E*4] | off
  float* q = (float*)d_ws;
  unsigned short* kbf = (unsigned short*)(q + (long)N_NODES * HU);
  unsigned short* vbf = kbf + (long)N_NODES * HU;
  unsigned short* gbf = vbf + (long)N_NODES * HU;
  float* scores = (float*)(gbf + (long)N_NODES * 256);
  int* off = (int*)(scores + (long)N_EDGES * NH);

  offsets_kernel<<<(N_EDGES + 255) / 256, 256, 0, stream>>>(src, off);
  qkvg_kernel<<<N_NODES / NPB, 128, 0, stream>>>(x, Wq, bq, Wk, bk, Wv, bv, be, We,
                                                 q, kbf, vbf, gbf);
  score_kernel<<<(N_EDGES * NH) / 256, 256, 0, stream>>>(ef, src, dst, q,
                                                         (const unsigned*)kbf,
                                                         (const unsigned*)gbf, scores);
  aggregate_kernel<<<N_NODES, 128, 0, stream>>>(off, dst, scores, vbf, Wo, bo, out);
}

// Round 6
// 625.195 us; speedup vs baseline: 1.1241x; 1.1010x over previous
//
#include <hip/hip_runtime.h>
#include <math.h>

#define N_NODES 50000
#define N_EDGES 800000
#define D_IN    128
#define ED_IN   64
#define HU      128   // H*U
#define NH      4
#define UD      32

#define NPB 16   // nodes per block in qkvg kernel

typedef float fx4 __attribute__((ext_vector_type(4)));

static __device__ __forceinline__ unsigned short f2bf(float f) {
  unsigned u = __float_as_uint(f);
  unsigned r = (u + 0x7FFFu + ((u >> 16) & 1u)) >> 16;
  return (unsigned short)r;
}
static __device__ __forceinline__ float bf_lo(unsigned u) {
  return __uint_as_float(u << 16);
}
static __device__ __forceinline__ float bf_hi(unsigned u) {
  return __uint_as_float(u & 0xFFFF0000u);
}
// 8-element dot: fp32 a0|a1 against 8 bf16 packed in uint4
static __device__ __forceinline__ float dot8(float4 a0, float4 a1, uint4 kk) {
  return a0.x * bf_lo(kk.x) + a0.y * bf_hi(kk.x)
       + a0.z * bf_lo(kk.y) + a0.w * bf_hi(kk.y)
       + a1.x * bf_lo(kk.z) + a1.y * bf_hi(kk.z)
       + a1.z * bf_lo(kk.w) + a1.w * bf_hi(kk.w);
}

// K0: segment offsets from sorted src. off[n] = lower_bound(src, n); off[N] = E.
__global__ __launch_bounds__(256) void offsets_kernel(
    const int* __restrict__ src, int* __restrict__ off) {
  const int e = blockIdx.x * 256 + threadIdx.x;
  if (e >= N_EDGES) return;
  const int s = src[e];
  const int prev = (e == 0) ? -1 : src[e - 1];
  for (int n = prev + 1; n <= s; ++n) off[n] = e;
  if (e == N_EDGES - 1)
    for (int n = s + 1; n <= N_NODES; ++n) off[n] = N_EDGES;
}

// K1: fused q/k/v projections + g matrix, writing the interleaved kg layout:
//   kg (ushort): node stride 384; head h at +h*96: [32 x k bf16][64 x g bf16]
//   q fp32 (bq+be folded); v bf16 [n][128]
__global__ __launch_bounds__(128) void qkvg_kernel(
    const float* __restrict__ x,
    const float* __restrict__ Wq, const float* __restrict__ bq,
    const float* __restrict__ Wk, const float* __restrict__ bk,
    const float* __restrict__ Wv, const float* __restrict__ bv,
    const float* __restrict__ be, const float* __restrict__ We,
    float* __restrict__ q, unsigned short* __restrict__ kg,
    unsigned short* __restrict__ vbf) {
  const int base = blockIdx.x * NPB;
  const int t = threadIdx.x;
  __shared__ float xs[NPB][D_IN];
  for (int j = 0; j < NPB; ++j)
    xs[j][t] = x[(long)(base + j) * D_IN + t];
  __syncthreads();
  float aq[NPB], ak[NPB], av[NPB];
  const float bqt = bq[t] + be[t], bkt = bk[t], bvt = bv[t];
#pragma unroll
  for (int j = 0; j < NPB; ++j) { aq[j] = bqt; ak[j] = bkt; av[j] = bvt; }
  for (int i = 0; i < D_IN; ++i) {
    const float wq = Wq[i * HU + t];
    const float wk = Wk[i * HU + t];
    const float wv = Wv[i * HU + t];
#pragma unroll
    for (int j = 0; j < NPB; ++j) {
      const float xi = xs[j][i];
      aq[j] += xi * wq; ak[j] += xi * wk; av[j] += xi * wv;
    }
  }
  const int h = t >> 5, u = t & 31;
#pragma unroll
  for (int j = 0; j < NPB; ++j) {
    const long nn = base + j;
    q[nn * HU + t] = aq[j];
    vbf[nn * HU + t] = f2bf(av[j]);
    kg[nn * 384 + h * 96 + u] = f2bf(ak[j]);
  }
  __syncthreads();
#pragma unroll
  for (int j = 0; j < NPB; ++j) xs[j][t] = ak[j];  // reuse xs as k staging
  __syncthreads();
  for (int r = 0; r < 2; ++r) {
    const int o = t + 128 * r;      // output index in [0,256)
    const int oh = o >> 6, oi = o & 63;
    float acc[NPB];
#pragma unroll
    for (int j = 0; j < NPB; ++j) acc[j] = 0.f;
    for (int u2 = 0; u2 < 32; ++u2) {
      const float w = We[oi * HU + oh * 32 + u2];
#pragma unroll
      for (int j = 0; j < NPB; ++j) acc[j] += w * xs[j][oh * 32 + u2];
    }
#pragma unroll
    for (int j = 0; j < NPB; ++j)
      kg[(long)(base + j) * 384 + oh * 96 + 32 + oi] = f2bf(acc[j]);
  }
}

// K2: one thread per (edge, head); 64 edges per 256-thread block.
// scores[e,h] = q'[s,h,:]·k[d,h,:] + ef[e,:]·g[d,h,:]
// k+g read as ONE contiguous 192B record; ef staged once via LDS (nontemporal).
__global__ __launch_bounds__(256) void score_kernel(
    const float* __restrict__ ef,
    const int* __restrict__ src, const int* __restrict__ dst,
    const float* __restrict__ q, const uint4* __restrict__ kg,
    float* __restrict__ scores) {
  __shared__ float efs[64][ED_IN + 1];
  const int t = threadIdx.x;
  const long ebase = (long)blockIdx.x * 64;
  const int e = (int)(ebase + (t >> 2));
  const int h = t & 3;
  const int s = src[e], d = dst[e];

  // one contiguous 192B record: 4 uint4 of k + 8 uint4 of g
  const uint4* kgp = kg + (long)d * 48 + h * 12;
  const uint4 kk0 = kgp[0], kk1 = kgp[1], kk2 = kgp[2], kk3 = kgp[3];
  uint4 gr[8];
#pragma unroll
  for (int c = 0; c < 8; ++c) gr[c] = kgp[4 + c];

  const float4* qp = (const float4*)(q + (long)s * HU + h * 32);
  const float4 q0 = qp[0], q1 = qp[1], q2 = qp[2], q3 = qp[3];
  const float4 q4 = qp[4], q5 = qp[5], q6 = qp[6], q7 = qp[7];

  // stage ef once: 64 rows x 64 floats; nontemporal (no reuse beyond block)
  const fx4* efb = (const fx4*)(ef + ebase * ED_IN);
#pragma unroll
  for (int r = 0; r < 4; ++r) {
    const int m = t + 256 * r;
    const fx4 vv = __builtin_nontemporal_load(efb + m);
    const int row = m >> 4, i0 = (m & 15) * 4;
    efs[row][i0] = vv.x; efs[row][i0 + 1] = vv.y;
    efs[row][i0 + 2] = vv.z; efs[row][i0 + 3] = vv.w;
  }
  __syncthreads();

  float p = dot8(q0, q1, kk0) + dot8(q2, q3, kk1)
          + dot8(q4, q5, kk2) + dot8(q6, q7, kk3);
  const float* er = efs[t >> 2];
#pragma unroll
  for (int c = 0; c < 8; ++c) {
    const float4 a0 = make_float4(er[c * 8 + 0], er[c * 8 + 1], er[c * 8 + 2], er[c * 8 + 3]);
    const float4 a1 = make_float4(er[c * 8 + 4], er[c * 8 + 5], er[c * 8 + 6], er[c * 8 + 7]);
    p += dot8(a0, a1, gr[c]);
  }
  __builtin_nontemporal_store(p, scores + (long)e * NH + h);
}

// K3: one WAVE per node (4 nodes per 256-thread block), barrier-free.
// Lane l: features 2l,2l+1 (head h=l>>4); softmax in 16-lane shuffle groups.
__global__ __launch_bounds__(256) void aggregate_kernel(
    const int* __restrict__ off, const int* __restrict__ dst,
    const float* __restrict__ scores, const unsigned* __restrict__ v2,
    const float* __restrict__ Wo, const float* __restrict__ bo,
    float* __restrict__ out) {
  const int wv = threadIdx.x >> 6, l = threadIdx.x & 63;
  const int n = blockIdx.x * 4 + wv;
  const int h = l >> 4, q16 = l & 15;
  __shared__ float att[4][HU];

  const int start = off[n], end = off[n + 1];
  float m = -INFINITY, lsum = 0.f, a0 = 0.f, a1 = 0.f;
  for (int cs = start; cs < end; cs += 16) {
    const int e = cs + q16;
    const bool live = (e < end);
    const float sc = live ? __builtin_nontemporal_load(scores + (long)e * NH + h)
                          : -INFINITY;
    const int dl = live ? dst[e] : 0;
    float mc = sc;
#pragma unroll
    for (int o = 8; o > 0; o >>= 1) mc = fmaxf(mc, __shfl_xor(mc, o, 16));
    const float nm = fmaxf(m, mc);          // finite: >=1 live edge per chunk
    const float corr = __expf(m - nm);      // 0 on first chunk
    const float w = __expf(sc - nm);        // 0 for dead lanes
    float ws = w;
#pragma unroll
    for (int o = 8; o > 0; o >>= 1) ws += __shfl_xor(ws, o, 16);
    lsum = lsum * corr + ws;
    a0 *= corr; a1 *= corr; m = nm;
    // fully unrolled: dead entries have w=0, dst=0 (harmless cached row-0 load)
#pragma unroll
    for (int j = 0; j < 16; ++j) {
      const float wj = __shfl(w, (l & 48) + j, 64);
      const int dj = __shfl(dl, (l & 48) + j, 64);
      const unsigned vr = v2[(long)dj * 64 + l];   // 256B coalesced row
      a0 += wj * bf_lo(vr);
      a1 += wj * bf_hi(vr);
    }
  }
  const float inv = (lsum > 0.f) ? 1.f / lsum : 0.f;
  att[wv][2 * l] = a0 * inv;
  att[wv][2 * l + 1] = a1 * inv;
  // wave-synchronous: same wave wrote these LDS entries, no barrier needed
  const int o = l & 31, half = l >> 5;
  float po = 0.f;
#pragma unroll
  for (int f = 0; f < 64; ++f)
    po += att[wv][half * 64 + f] * Wo[(half * 64 + f) * UD + o];
  po += __shfl_down(po, 32, 64);
  if (l < 32) out[(long)n * UD + l] = fmaxf(po + bo[l], 0.f);
}

extern "C" void kernel_launch(void* const* d_in, const int* in_sizes, int n_in,
                              void* d_out, int out_size, void* d_ws, size_t ws_size,
                              hipStream_t stream) {
  const float* x  = (const float*)d_in[0];
  const int*   ei = (const int*)d_in[1];
  const float* ef = (const float*)d_in[2];
  const float* Wq = (const float*)d_in[3];
  const float* bq = (const float*)d_in[4];
  const float* Wk = (const float*)d_in[5];
  const float* bk = (const float*)d_in[6];
  const float* Wv = (const float*)d_in[7];
  const float* bv = (const float*)d_in[8];
  const float* We = (const float*)d_in[9];
  const float* be = (const float*)d_in[10];
  const float* Wo = (const float*)d_in[11];
  const float* bo = (const float*)d_in[12];
  float* out = (float*)d_out;

  const int* src = ei;             // edge_index[0]
  const int* dst = ei + N_EDGES;   // edge_index[1]

  // ws: q fp32 [N*128] | kg ushort [N*384] | vbf ushort [N*128] | scores [E*4] | off
  float* q = (float*)d_ws;
  unsigned short* kg = (unsigned short*)(q + (long)N_NODES * HU);
  unsigned short* vbf = kg + (long)N_NODES * 384;
  float* scores = (float*)(vbf + (long)N_NODES * HU);
  int* off = (int*)(scores + (long)N_EDGES * NH);

  offsets_kernel<<<(N_EDGES + 255) / 256, 256, 0, stream>>>(src, off);
  qkvg_kernel<<<N_NODES / NPB, 128, 0, stream>>>(x, Wq, bq, Wk, bk, Wv, bv, be, We,
                                                 q, kg, vbf);
  score_kernel<<<N_EDGES / 64, 256, 0, stream>>>(ef, src, dst, q,
                                                 (const uint4*)kg, scores);
  aggregate_kernel<<<N_NODES / 4, 256, 0, stream>>>(off, dst, scores,
                                                    (const unsigned*)vbf, Wo, bo, out);
}